// Round 2
// 694.868 us; speedup vs baseline: 1.4594x; 1.4594x over previous
//
#include <hip/hip_runtime.h>

// SAvgPool2d (2x2, stride 2) + LIF spiking scan over T. MI355X gfx950.
// x: [B=16, C=64, H=64, W=64, T=32] fp32, T innermost. out: [16,64,32,32,32].
//
// v2b: full-line-coalesced rework (v2 + compile fix: nontemporal builtins
// need native ext_vector types, not HIP_vector_type).
//
// The round-0 kernel (477 us) moved 1.77 GB of HBM traffic vs 604 MB ideal
// (2.7x read amp, 4.6x write amp): 16B/lane loads at 256B lane stride rely on
// cross-instruction cache-line reuse that dies in L1/L2 (concurrent working
// set ~12 MiB/XCD vs 4 MiB L2).
//
// Structure (per block = 256 threads = one bc plane x 8 hp rows):
//  phase 1: thread (wp=tid>>3, tc=tid&7) loads the four float4s
//           (row 2hp / 2hp+1) x (w=2wp / 2wp+1) for its t-quad. Every load
//           instruction's footprint is fully-consumed 128B blocks; every
//           input byte loaded exactly once. Pool in f64 with association
//           ((a+b)+c)+d (same as the passing round-0 kernel), store pooled
//           f64 to LDS (XOR-swizzled t8 -> <=2-way banks).
//  phase 2: thread (hpl=tid>>5, wp=tid&31) reads its contiguous pooled row
//           from LDS (b128), runs the f64 LIF scan in registers.
//  phase 3: spikes staged to LDS (XOR-swizzled), then 8x 4KiB-contiguous
//           nontemporal float4 stores per block. Ideal HBM: 512 MiB + 64 MiB.
//
// NUMERICS: pooled = (((a+b)+c)+d)*0.25 in f64, scan u = u - s*th + p in f64
// -- identical op order to the absmax==0.0 kernel (s*th is exact, so FMA
// contraction cannot change rounding).

typedef float f32x4 __attribute__((ext_vector_type(4)));

constexpr int Bn = 16;
constexpr int Cn = 64;
constexpr int Hn = 64;
constexpr int Wn = 64;
constexpr int Tn = 32;
constexpr int Hp = Hn / 2;   // 32
constexpr int Wp = Wn / 2;   // 32
constexpr int HPB = 8;       // hp rows per block
constexpr int THREADS = 256;
constexpr int NBLK = (Bn * Cn) * (Hp / HPB);  // 1024 * 4 = 4096

__global__ void __launch_bounds__(256, 2)
savgpool_spike_v2(const float* __restrict__ x,
                  const float* __restrict__ thresh,
                  float* __restrict__ out) {
  // pooled f64 [HPB][Wp][16 x double2] = 8*32*16*16 B = 64 KiB.
  // Reused afterwards as f32x4 stage[256][8] (32 KiB) for the output.
  __shared__ double2 lds[HPB * Wp * 16];

  const int tid  = threadIdx.x;
  const int bc   = blockIdx.x >> 2;   // 0..1023
  const int hseg = blockIdx.x & 3;    // 0..3
  const int hp0  = hseg * HPB;

  const double th = (double)thresh[0];

  // ---------------- phase 1: coalesced load + f64 pool + LDS stage ----------
  const int k  = tid >> 3;            // wp this thread pools: 0..31
  const int tc = tid & 7;             // t-quad: 0..7
  const int ksw = k & 7;              // LDS swizzle for this wp row

  const size_t planeF4 = (size_t)Hn * Wn * Tn / 4;  // 32768 f32x4 per (b,c)
  const size_t rowF4   = (size_t)Wn * Tn / 4;       // 512 f32x4 per H row
  const f32x4* xp = reinterpret_cast<const f32x4*>(x) + (size_t)bc * planeF4;

#pragma unroll
  for (int c = 0; c < HPB; ++c) {
    const int h0 = (hp0 + c) * 2;
    const f32x4* r0 = xp + (size_t)h0 * rowF4;  // row 2hp
    const f32x4* r1 = r0 + rowF4;               // row 2hp+1
    const int fi = 16 * k + tc;                 // f32x4 idx of (w=2wp, tquad tc)

    const f32x4 A0 = __builtin_nontemporal_load(r0 + fi);      // (2hp,   2wp  )
    const f32x4 A1 = __builtin_nontemporal_load(r0 + fi + 8);  // (2hp,   2wp+1)
    const f32x4 B0 = __builtin_nontemporal_load(r1 + fi);      // (2hp+1, 2wp  )
    const f32x4 B1 = __builtin_nontemporal_load(r1 + fi + 8);  // (2hp+1, 2wp+1)

    // f64 pool, association identical to the round-0 kernel: ((a+b)+c)+d
    const double p0 =
        ((((double)A0.x + (double)A1.x) + (double)B0.x) + (double)B1.x) * 0.25;
    const double p1 =
        ((((double)A0.y + (double)A1.y) + (double)B0.y) + (double)B1.y) * 0.25;
    const double p2 =
        ((((double)A0.z + (double)A1.z) + (double)B0.z) + (double)B1.z) * 0.25;
    const double p3 =
        ((((double)A0.w + (double)A1.w) + (double)B0.w) + (double)B1.w) * 0.25;

    // pooled[c][k][t8] with t8 XOR-swizzle (<=2-way banks on b128)
    const int base16 = (c * Wp + k) * 16;
    lds[base16 + ((2 * tc)     ^ ksw)] = make_double2(p0, p1);  // t = 4tc..4tc+1
    lds[base16 + ((2 * tc + 1) ^ ksw)] = make_double2(p2, p3);  // t = 4tc+2..+3
  }

  __syncthreads();

  // ---------------- phase 2: f64 LIF scan from LDS ---------------------------
  const int hpl = tid >> 5;           // 0..7  (== chunk c)
  const int wp  = tid & 31;
  const int rbase = (hpl * Wp + wp) * 16;
  const int rsw   = wp & 7;

  double u = 0.0, s = 0.0;
  float sp[Tn];
#pragma unroll
  for (int t8 = 0; t8 < 16; ++t8) {
    const double2 pv = lds[rbase + (t8 ^ rsw)];
    u = u - s * th + pv.x; s = (u > 0.0) ? 1.0 : 0.0; sp[2 * t8]     = (float)s;
    u = u - s * th + pv.y; s = (u > 0.0) ? 1.0 : 0.0; sp[2 * t8 + 1] = (float)s;
  }

  __syncthreads();  // all pooled reads done before overwriting LDS

  // ---------------- phase 3: stage spikes + coalesced writeout ---------------
  // stage[loc_l][t4] f32x4, t4 XOR-swizzled by loc_l&7 (<=2-way banks)
  f32x4* st = reinterpret_cast<f32x4*>(lds);
  const int tsw = tid & 7;
#pragma unroll
  for (int t4 = 0; t4 < 8; ++t4) {
    f32x4 v;
    v.x = sp[4 * t4];
    v.y = sp[4 * t4 + 1];
    v.z = sp[4 * t4 + 2];
    v.w = sp[4 * t4 + 3];
    st[tid * 8 + (t4 ^ tsw)] = v;
  }

  __syncthreads();

  // block's 256 locs are contiguous in out: 32 KiB, written as 8 x 4 KiB
  const size_t locBase = ((size_t)bc * Hp + hp0) * Wp;
  f32x4* o = reinterpret_cast<f32x4*>(out) + locBase * 8;
#pragma unroll
  for (int i = 0; i < 8; ++i) {
    const int ll = i * 32 + (tid >> 3);            // local loc this f4 belongs to
    const f32x4 v = st[ll * 8 + ((tid & 7) ^ (ll & 7))];
    __builtin_nontemporal_store(v, o + i * 256 + tid);
  }
}

extern "C" void kernel_launch(void* const* d_in, const int* in_sizes, int n_in,
                              void* d_out, int out_size, void* d_ws, size_t ws_size,
                              hipStream_t stream) {
  const float* in0 = (const float*)d_in[0];
  const float* in1 = (const float*)d_in[1];
  const float* x      = (in_sizes[0] == 1) ? in1 : in0;
  const float* thresh = (in_sizes[0] == 1) ? in0 : in1;
  float* out = (float*)d_out;

  savgpool_spike_v2<<<NBLK, THREADS, 0, stream>>>(x, thresh, out);
}